// Round 13
// baseline (1572.226 us; speedup 1.0000x reference)
//
#include <hip/hip_runtime.h>
#include <hip/hip_bf16.h>
#include <math.h>

// Split-bf16 MFMA exact-KNN (K=32) + inverse-squared-distance weighting.
// points:[16384,64] features:[20000,64] targets:[20000] -> out:[16384]
//
// Round 13: MLP/latency attack on the R10 structure.
//  - tau via two-pass 8b+8b histogram over a 4096-row sample (32KB LDS,
//    overlaid by candidates) -> no 132KB smp array; CAP 576->384.
//  - LDS ~74KB -> 2 blocks/CU -> 8 waves/SIMD (2x memory parallelism).
//  - phase 2 scans m in two 2.57MB halves -> per-half working set fits a
//    4MB XCD L2 -> L3-latency stream becomes L2-latency stream.
// Selection semantics identical to R10 (16-bit tau bin upper edge, exact
// rank + index tie-break among candidates).

#define NQ   16384
#define MM   20000
#define DD   64
#define KK   32
#define MPAD 20032
#define NCH  (MPAD / 64)   // 313
#define NW   16            // waves per block
#define QB   32            // queries per block
#define CAP  384           // E~160 (4096-sample tau) + ~7 sigma
#define HCH  157           // half-split of the chunk range

typedef __attribute__((ext_vector_type(8))) short bf16x8;
typedef __attribute__((ext_vector_type(4))) float f32x4;

// ---- workspace layout (bytes) ----
#define OFF_FH 0
#define SZ_FP  (MPAD * DD * 2)
#define OFF_FL (OFF_FH + SZ_FP)
#define OFF_FN (OFF_FL + SZ_FP)
#define SZ_FN  (MPAD * 4)
#define OFF_QH (OFF_FN + SZ_FN)
#define SZ_QP  (NQ * DD * 2)
#define OFF_QL (OFF_QH + SZ_QP)
#define OFF_QN (OFF_QL + SZ_QP)
#define SZ_QN  (NQ * 4)
#define WS_REQ (OFF_QN + SZ_QN)

__device__ __forceinline__ unsigned int bf16_rne(float x) {
    unsigned int xb = __float_as_uint(x);
    return (xb + 0x7fffu + ((xb >> 16) & 1u)) & 0xffff0000u;
}
__device__ __forceinline__ unsigned enc32(float f) {
    unsigned b = __float_as_uint(f);
    return (b & 0x80000000u) ? ~b : (b | 0x80000000u);
}
__device__ __forceinline__ float dec32(unsigned k) {
    unsigned b = (k & 0x80000000u) ? (k & 0x7FFFFFFFu) : ~k;
    return __uint_as_float(b);
}

__global__ void prep_split(const float* __restrict__ src,
                           unsigned short* __restrict__ ph,
                           unsigned short* __restrict__ pl,
                           float* __restrict__ nrm, int nrows_real) {
    const int e = blockIdx.x * 256 + threadIdx.x;
    const int m = e >> 6;
    const int lane = threadIdx.x & 63;
    const bool real = (m < nrows_real);
    float x = real ? src[e] : 0.f;
    unsigned int hb = bf16_rne(x);
    float xh = __uint_as_float(hb);
    unsigned int lb = bf16_rne(x - xh);
    ph[e] = (unsigned short)(hb >> 16);
    pl[e] = (unsigned short)(lb >> 16);
    float s = x * x;
    #pragma unroll
    for (int o = 32; o >= 1; o >>= 1) s += __shfl_xor(s, o);
    if (lane == 0) nrm[m] = real ? s : __builtin_inff();
}

// one subtile: 5 loads, 16 MFMA (4 independent chains), both q-groups.
// defines sA0..sA3 (group q), sB0..sB3 (group 16+q), rb4.
#define SUBTILE2(c_, t_)                                                       \
    const int frow = (c_) * 64 + (t_) * 16 + q;                                \
    const unsigned short* phh = Fh + (size_t)frow * DD + kof;                  \
    const unsigned short* pll = Fl + (size_t)frow * DD + kof;                  \
    const bf16x8 Ah0 = *(const bf16x8*)(phh);                                  \
    const bf16x8 Ah1 = *(const bf16x8*)(phh + 32);                             \
    const bf16x8 Al0 = *(const bf16x8*)(pll);                                  \
    const bf16x8 Al1 = *(const bf16x8*)(pll + 32);                             \
    const f32x4  fnv = *(const f32x4*)(fn + (c_) * 64 + (t_) * 16 + hgrp * 4); \
    f32x4 a0 = {0.f,0.f,0.f,0.f}, b0 = {0.f,0.f,0.f,0.f};                      \
    f32x4 a1 = {0.f,0.f,0.f,0.f}, b1 = {0.f,0.f,0.f,0.f};                      \
    a0 = __builtin_amdgcn_mfma_f32_16x16x32_bf16(Ah0, qh0A, a0, 0, 0, 0);      \
    b0 = __builtin_amdgcn_mfma_f32_16x16x32_bf16(Ah0, ql0A, b0, 0, 0, 0);      \
    a1 = __builtin_amdgcn_mfma_f32_16x16x32_bf16(Ah0, qh0B, a1, 0, 0, 0);      \
    b1 = __builtin_amdgcn_mfma_f32_16x16x32_bf16(Ah0, ql0B, b1, 0, 0, 0);      \
    a0 = __builtin_amdgcn_mfma_f32_16x16x32_bf16(Ah1, qh1A, a0, 0, 0, 0);      \
    b0 = __builtin_amdgcn_mfma_f32_16x16x32_bf16(Ah1, ql1A, b0, 0, 0, 0);      \
    a1 = __builtin_amdgcn_mfma_f32_16x16x32_bf16(Ah1, qh1B, a1, 0, 0, 0);      \
    b1 = __builtin_amdgcn_mfma_f32_16x16x32_bf16(Ah1, ql1B, b1, 0, 0, 0);      \
    a0 = __builtin_amdgcn_mfma_f32_16x16x32_bf16(Al0, qh0A, a0, 0, 0, 0);      \
    b0 = __builtin_amdgcn_mfma_f32_16x16x32_bf16(Al0, ql0A, b0, 0, 0, 0);      \
    a1 = __builtin_amdgcn_mfma_f32_16x16x32_bf16(Al0, qh0B, a1, 0, 0, 0);      \
    b1 = __builtin_amdgcn_mfma_f32_16x16x32_bf16(Al0, ql0B, b1, 0, 0, 0);      \
    a0 = __builtin_amdgcn_mfma_f32_16x16x32_bf16(Al1, qh1A, a0, 0, 0, 0);      \
    b0 = __builtin_amdgcn_mfma_f32_16x16x32_bf16(Al1, ql1A, b0, 0, 0, 0);      \
    a1 = __builtin_amdgcn_mfma_f32_16x16x32_bf16(Al1, qh1B, a1, 0, 0, 0);      \
    b1 = __builtin_amdgcn_mfma_f32_16x16x32_bf16(Al1, ql1B, b1, 0, 0, 0);      \
    const float sA0 = fnv[0] - 2.f * (a0[0] + b0[0]);                          \
    const float sA1 = fnv[1] - 2.f * (a0[1] + b0[1]);                          \
    const float sA2 = fnv[2] - 2.f * (a0[2] + b0[2]);                          \
    const float sA3 = fnv[3] - 2.f * (a0[3] + b0[3]);                          \
    const float sB0 = fnv[0] - 2.f * (a1[0] + b1[0]);                          \
    const float sB1 = fnv[1] - 2.f * (a1[1] + b1[1]);                          \
    const float sB2 = fnv[2] - 2.f * (a1[2] + b1[2]);                          \
    const float sB3 = fnv[3] - 2.f * (a1[3] + b1[3]);                          \
    const int rb4 = (c_) * 64 + (t_) * 16 + hgrp * 4;

#define GATE2(qq_, tau_, s0_, s1_, s2_, s3_) {                                 \
    const float sv_[4] = {s0_, s1_, s2_, s3_};                                 \
    _Pragma("unroll")                                                          \
    for (int j_ = 0; j_ < 4; ++j_) {                                           \
        if (sv_[j_] <= (tau_)) {                                               \
            const int p_ = atomicAdd(&cnt[qq_], 1);                            \
            if (p_ < CAP) {                                                    \
                bufd[(qq_) * CAP + p_] = sv_[j_];                              \
                bufi[(qq_) * CAP + p_] = (unsigned short)(rb4 + j_);           \
            }                                                                  \
        }                                                                      \
    }                                                                          \
}

// histogram both q-groups' 4 values each; bin extractor BX_(key32)
#define HIST8(BX_, PRED_) {                                                    \
    const unsigned kA0 = enc32(sA0), kA1 = enc32(sA1);                         \
    const unsigned kA2 = enc32(sA2), kA3 = enc32(sA3);                         \
    const unsigned kB0 = enc32(sB0), kB1 = enc32(sB1);                         \
    const unsigned kB2 = enc32(sB2), kB3 = enc32(sB3);                         \
    if (PRED_(kA0, q))      atomicAdd(&hist[q * 256 + BX_(kA0)], 1);           \
    if (PRED_(kA1, q))      atomicAdd(&hist[q * 256 + BX_(kA1)], 1);           \
    if (PRED_(kA2, q))      atomicAdd(&hist[q * 256 + BX_(kA2)], 1);           \
    if (PRED_(kA3, q))      atomicAdd(&hist[q * 256 + BX_(kA3)], 1);           \
    if (PRED_(kB0, 16 + q)) atomicAdd(&hist[(16 + q) * 256 + BX_(kB0)], 1);    \
    if (PRED_(kB1, 16 + q)) atomicAdd(&hist[(16 + q) * 256 + BX_(kB1)], 1);    \
    if (PRED_(kB2, 16 + q)) atomicAdd(&hist[(16 + q) * 256 + BX_(kB2)], 1);    \
    if (PRED_(kB3, 16 + q)) atomicAdd(&hist[(16 + q) * 256 + BX_(kB3)], 1);    \
}

#define BX_TOP(k_)  ((k_) >> 24)
#define BX_MID(k_)  (((k_) >> 16) & 0xFFu)
#define PR_ALL(k_, qq_)  (1)
#define PR_BIN(k_, qq_)  (((k_) >> 24) == (unsigned)bstar[qq_])

// wave-level select over hist[qq][0..255]: first bin where base+cum >= KK.
// All lanes get (selbin, below). h-values loaded per lane (4 bins/lane).
#define SELECT256(qq_, base_, SELB_, BELOW_) {                                 \
    const int b0_ = lane * 4;                                                  \
    const int h0_ = hist[(qq_) * 256 + b0_ + 0];                               \
    const int h1_ = hist[(qq_) * 256 + b0_ + 1];                               \
    const int h2_ = hist[(qq_) * 256 + b0_ + 2];                               \
    const int h3_ = hist[(qq_) * 256 + b0_ + 3];                               \
    const int c4_ = h0_ + h1_ + h2_ + h3_;                                     \
    int pref_ = c4_;                                                           \
    _Pragma("unroll")                                                          \
    for (int of_ = 1; of_ < 64; of_ <<= 1) {                                   \
        const int t_ = __shfl_up(pref_, of_);                                  \
        if (lane >= of_) pref_ += t_;                                          \
    }                                                                          \
    const unsigned long long mk_ = __ballot((base_) + pref_ >= KK);            \
    const int sel_ = __builtin_ctzll(mk_ | 0x8000000000000000ull);             \
    const int cb_  = __shfl(pref_ - c4_, sel_) + (base_);                      \
    const int g0_ = __shfl(h0_, sel_), g1_ = __shfl(h1_, sel_);                \
    const int g2_ = __shfl(h2_, sel_);                                         \
    int bs_, bl_;                                                              \
    if      (cb_ + g0_ >= KK)             { bs_ = 0; bl_ = cb_; }              \
    else if (cb_ + g0_ + g1_ >= KK)       { bs_ = 1; bl_ = cb_ + g0_; }        \
    else if (cb_ + g0_ + g1_ + g2_ >= KK) { bs_ = 2; bl_ = cb_ + g0_ + g1_; }  \
    else                                  { bs_ = 3; bl_ = cb_ + g0_ + g1_ + g2_; } \
    SELB_ = sel_ * 4 + bs_;                                                    \
    BELOW_ = bl_;                                                              \
}

__global__ __launch_bounds__(1024, 8) void knn_filter32(
    const unsigned short* __restrict__ Fh, const unsigned short* __restrict__ Fl,
    const float* __restrict__ fn,
    const unsigned short* __restrict__ Qh, const unsigned short* __restrict__ Ql,
    const float* __restrict__ qn,
    const float* __restrict__ targets, float* __restrict__ out)
{
    // pool: phase1 = hist u32[32][256] (32KB); phase2/3 = bufd f32[32][CAP]
    // (48KB) + bufi u16[32][CAP] (24KB) = 72KB. pool = 73728 B.
    __shared__ __align__(16) unsigned char pool[QB * CAP * 6];
    __shared__ float tau_f[QB];
    __shared__ int   cnt[QB];
    __shared__ int   bstar[QB];
    __shared__ int   cbel[QB];

    int*            hist = (int*)pool;
    float*          bufd = (float*)pool;
    unsigned short* bufi = (unsigned short*)(pool + QB * CAP * 4);

    const int tid  = threadIdx.x;
    const int lane = tid & 63;
    const int w    = tid >> 6;          // 0..15
    const int qbase = blockIdx.x * QB;
    const int q    = lane & 15;
    const int hgrp = lane >> 4;
    const int kof  = hgrp * 8;

    if (tid < QB) cnt[tid] = 0;
    #pragma unroll
    for (int i = 0; i < 8; ++i) hist[tid + i * 1024] = 0;

    // stationary Q^T fragments, two query groups
    const int qrow0 = qbase + q;
    const int qrow1 = qbase + 16 + q;
    const bf16x8 qh0A = *(const bf16x8*)(Qh + (size_t)qrow0 * DD + kof);
    const bf16x8 qh1A = *(const bf16x8*)(Qh + (size_t)qrow0 * DD + kof + 32);
    const bf16x8 ql0A = *(const bf16x8*)(Ql + (size_t)qrow0 * DD + kof);
    const bf16x8 ql1A = *(const bf16x8*)(Ql + (size_t)qrow0 * DD + kof + 32);
    const bf16x8 qh0B = *(const bf16x8*)(Qh + (size_t)qrow1 * DD + kof);
    const bf16x8 qh1B = *(const bf16x8*)(Qh + (size_t)qrow1 * DD + kof + 32);
    const bf16x8 ql0B = *(const bf16x8*)(Ql + (size_t)qrow1 * DD + kof);
    const bf16x8 ql1B = *(const bf16x8*)(Ql + (size_t)qrow1 * DD + kof + 32);
    __syncthreads();

    // ===== phase 1a: coarse histogram over sample chunks 0..63 =============
    #pragma unroll
    for (int cc = 0; cc < 4; ++cc) {
        const int chunk = w * 4 + cc;
        #pragma unroll
        for (int t = 0; t < 4; ++t) {
            SUBTILE2(chunk, t)
            (void)rb4;
            HIST8(BX_TOP, PR_ALL)
        }
    }
    __syncthreads();

    // ===== phase 1b: coarse select (wave w owns queries 2w, 2w+1) ==========
    #pragma unroll
    for (int e = 0; e < 2; ++e) {
        const int qq = w * 2 + e;
        int sb, bl;
        SELECT256(qq, 0, sb, bl)
        if (lane == 0) { bstar[qq] = sb; cbel[qq] = bl; }
    }
    __syncthreads();

    // ===== phase 1c: zero hist for fine pass ===============================
    #pragma unroll
    for (int i = 0; i < 8; ++i) hist[tid + i * 1024] = 0;
    __syncthreads();

    // ===== phase 1d: fine histogram (only values in the coarse bin) ========
    #pragma unroll
    for (int cc = 0; cc < 4; ++cc) {
        const int chunk = w * 4 + cc;
        #pragma unroll
        for (int t = 0; t < 4; ++t) {
            SUBTILE2(chunk, t)
            (void)rb4;
            HIST8(BX_MID, PR_BIN)
        }
    }
    __syncthreads();

    // ===== phase 1e: fine select -> tau ====================================
    #pragma unroll
    for (int e = 0; e < 2; ++e) {
        const int qq = w * 2 + e;
        int sb, bl;
        SELECT256(qq, cbel[qq], sb, bl)
        (void)bl;
        if (lane == 0) {
            const unsigned key16 = ((unsigned)bstar[qq] << 8) | (unsigned)sb;
            tau_f[qq] = (key16 >= 0xFFFFu) ? __builtin_inff()
                                           : dec32((key16 + 1u) << 16);
        }
    }
    __syncthreads();

    // ===== phase 2: full scan in two L2-resident m-halves ==================
    const float tauR0 = tau_f[q];
    const float tauR1 = tau_f[16 + q];
    for (int c = w; c < HCH; c += NW) {
        #pragma unroll
        for (int t = 0; t < 4; ++t) {
            SUBTILE2(c, t)
            GATE2(q,      tauR0, sA0, sA1, sA2, sA3)
            GATE2(16 + q, tauR1, sB0, sB1, sB2, sB3)
        }
    }
    for (int c = HCH + w; c < NCH; c += NW) {
        #pragma unroll
        for (int t = 0; t < 4; ++t) {
            SUBTILE2(c, t)
            GATE2(q,      tauR0, sA0, sA1, sA2, sA3)
            GATE2(16 + q, tauR1, sB0, sB1, sB2, sB3)
        }
    }
    __syncthreads();

    // ===== phase 3: exact rank + weighted sum (2 q per wave) ===============
    #pragma unroll
    for (int e = 0; e < 2; ++e) {
        const int q3 = w * 2 + e;
        const int n  = min(cnt[q3], CAP);
        const float qnv = qn[qbase + q3];

        float    ms[6]; unsigned kk[6]; unsigned short miu[6];
        #pragma unroll
        for (int u = 0; u < 6; ++u) {
            const int j = lane + u * 64;
            const bool v = (j < n);
            ms[u]  = v ? bufd[q3 * CAP + j] : __builtin_inff();
            miu[u] = v ? bufi[q3 * CAP + j] : (unsigned short)0xFFFFu;
            kk[u]  = enc32(ms[u]);
        }
        unsigned lo = 0;
        for (int bit = 31; bit >= 0; --bit) {
            const unsigned trial = lo | (1u << bit);
            int c = 0;
            #pragma unroll
            for (int u = 0; u < 6; ++u) c += (kk[u] < trial);
            #pragma unroll
            for (int o = 32; o >= 1; o >>= 1) c += __shfl_xor(c, o);
            if (c < KK) lo = trial;
        }
        int c0 = 0, tcnt = 0;
        #pragma unroll
        for (int u = 0; u < 6; ++u) { c0 += (kk[u] < lo); tcnt += (kk[u] == lo); }
        #pragma unroll
        for (int o = 32; o >= 1; o >>= 1) {
            c0 += __shfl_xor(c0, o); tcnt += __shfl_xor(tcnt, o);
        }
        const int kprime = KK - c0;
        unsigned ilo = 0xFFFFu;
        if (tcnt != kprime) {
            ilo = 0;
            for (int bit = 15; bit >= 0; --bit) {
                const unsigned trial = ilo | (1u << bit);
                int c = 0;
                #pragma unroll
                for (int u = 0; u < 6; ++u)
                    c += ((kk[u] == lo) && ((unsigned)miu[u] < trial));
                #pragma unroll
                for (int o = 32; o >= 1; o >>= 1) c += __shfl_xor(c, o);
                if (c < kprime) ilo = trial;
            }
        }
        float nume = 0.f, deno = 0.f;
        #pragma unroll
        for (int u = 0; u < 6; ++u) {
            const bool inc = (kk[u] < lo) ||
                             ((kk[u] == lo) && ((unsigned)miu[u] <= ilo));
            if (inc) {
                const float d2 = fmaxf(qnv + ms[u], 0.f);
                const float wv = 1.f / (d2 + 1e-4f);
                nume = fmaf(wv, targets[miu[u]], nume);
                deno += wv;
            }
        }
        #pragma unroll
        for (int o = 32; o >= 1; o >>= 1) {
            nume += __shfl_xor(nume, o);
            deno += __shfl_xor(deno, o);
        }
        if (lane == 0) out[qbase + q3] = nume / fmaxf(deno, 1e-9f);
    }
}

// ---------------- fallback: round-1 exact fp32 vector kernel ----------------
#define BQ 32
#define WQ 8
__global__ __launch_bounds__(256) void hp_knn_kernel(
    const float* __restrict__ points, const float* __restrict__ features,
    const float* __restrict__ targets, float* __restrict__ out)
{
    __shared__ __align__(16) float Qs[BQ][DD];
    __shared__ float qn_s[BQ];
    __shared__ float topd[BQ][KK];
    __shared__ int   topi[BQ][KK];
    const int tid = threadIdx.x, lane = tid & 63, wv = tid >> 6, qb = wv * WQ;
    {
        const float4* src = (const float4*)(points + (size_t)blockIdx.x * BQ * DD);
        float4* dst = (float4*)&Qs[0][0];
        #pragma unroll
        for (int i = 0; i < (BQ * DD / 4) / 256; ++i) dst[tid + i * 256] = src[tid + i * 256];
    }
    for (int i = tid; i < BQ * KK; i += 256) { (&topd[0][0])[i] = __builtin_inff(); (&topi[0][0])[i] = 0; }
    __syncthreads();
    if (tid < BQ) {
        float s = 0.f;
        #pragma unroll
        for (int d = 0; d < DD; ++d) s = fmaf(Qs[tid][d], Qs[tid][d], s);
        qn_s[tid] = s;
    }
    __syncthreads();
    for (int c = 0; c < (MM + 63) / 64; ++c) {
        const int m = c * 64 + lane, mc = (m < MM) ? m : (MM - 1);
        float f[DD];
        const float4* fr = (const float4*)(features + (size_t)mc * DD);
        #pragma unroll
        for (int b = 0; b < DD / 4; ++b) { float4 v = fr[b]; f[4*b]=v.x; f[4*b+1]=v.y; f[4*b+2]=v.z; f[4*b+3]=v.w; }
        float fnv = 0.f;
        #pragma unroll
        for (int d = 0; d < DD; ++d) fnv = fmaf(f[d], f[d], fnv);
        float d2v[WQ];
        #pragma unroll
        for (int qi = 0; qi < WQ; ++qi) {
            const float4* qr = (const float4*)&Qs[qb + qi][0];
            float a0=0,a1=0,a2=0,a3=0;
            #pragma unroll
            for (int b = 0; b < DD / 4; ++b) {
                float4 q4 = qr[b];
                a0 = fmaf(q4.x, f[4*b], a0); a1 = fmaf(q4.y, f[4*b+1], a1);
                a2 = fmaf(q4.z, f[4*b+2], a2); a3 = fmaf(q4.w, f[4*b+3], a3);
            }
            float d2 = fmaxf(qn_s[qb+qi] + fnv - 2.f*((a0+a1)+(a2+a3)), 0.f);
            d2v[qi] = (m < MM) ? d2 : __builtin_inff();
        }
        #pragma unroll
        for (int qi = 0; qi < WQ; ++qi) {
            const int q = qb + qi;
            unsigned long long ball = __ballot(d2v[qi] < topd[q][KK-1]);
            while (ball) {
                const int j = __builtin_ctzll(ball); ball &= ball - 1;
                const float dval = __shfl(d2v[qi], j); const int mval = c * 64 + j;
                if (lane < KK) {
                    const float cur = topd[q][lane];
                    if (cur > dval) {
                        const float pd = (lane > 0) ? topd[q][lane-1] : -1.f;
                        const int   pi = (lane > 0) ? topi[q][lane-1] : 0;
                        const bool tp = (pd > dval);
                        topd[q][lane] = tp ? pd : dval; topi[q][lane] = tp ? pi : mval;
                    }
                }
            }
        }
    }
    #pragma unroll
    for (int qi = 0; qi < WQ; ++qi) {
        const int q = qb + qi;
        float wsum = 0.f, wt = 0.f;
        if (lane < KK) {
            const float ww = 1.f / (topd[q][lane] + 1e-4f);
            wsum = ww; wt = ww * targets[topi[q][lane]];
        }
        #pragma unroll
        for (int o = 32; o >= 1; o >>= 1) { wsum += __shfl_xor(wsum, o); wt += __shfl_xor(wt, o); }
        if (lane == 0) out[(size_t)blockIdx.x * BQ + q] = wt / fmaxf(wsum, 1e-9f);
    }
}

extern "C" void kernel_launch(void* const* d_in, const int* in_sizes, int n_in,
                              void* d_out, int out_size, void* d_ws, size_t ws_size,
                              hipStream_t stream) {
    const float* points   = (const float*)d_in[0];
    const float* features = (const float*)d_in[1];
    const float* targets  = (const float*)d_in[2];
    float* out = (float*)d_out;

    if (ws_size < (size_t)WS_REQ) {
        hp_knn_kernel<<<dim3(NQ / BQ), dim3(256), 0, stream>>>(points, features, targets, out);
        return;
    }
    char* ws = (char*)d_ws;
    unsigned short* Fh = (unsigned short*)(ws + OFF_FH);
    unsigned short* Fl = (unsigned short*)(ws + OFF_FL);
    float*          fn = (float*)(ws + OFF_FN);
    unsigned short* Qh = (unsigned short*)(ws + OFF_QH);
    unsigned short* Ql = (unsigned short*)(ws + OFF_QL);
    float*          qnp= (float*)(ws + OFF_QN);

    prep_split<<<dim3(MPAD * DD / 256), dim3(256), 0, stream>>>(features, Fh, Fl, fn, MM);
    prep_split<<<dim3(NQ * DD / 256),  dim3(256), 0, stream>>>(points,   Qh, Ql, qnp, NQ);
    knn_filter32<<<dim3(NQ / QB), dim3(1024), 0, stream>>>(Fh, Fl, fn, Qh, Ql, qnp, targets, out);
}

// Round 14
// 494.627 us; speedup vs baseline: 3.1786x; 3.1786x over previous
//
#include <hip/hip_runtime.h>
#include <hip/hip_bf16.h>
#include <math.h>

// Split-bf16 MFMA exact-KNN (K=32) + inverse-squared-distance weighting.
// points:[16384,64] features:[20000,64] targets:[20000] -> out:[16384]
//
// Round 14 = Round 13 structure with two fixes:
//  - __launch_bounds__(1024) WITHOUT min-waves pin (R13's ",8" forced
//    VGPR=32 -> scratch spill, FETCH 4.4GB). Natural allocation is 64
//    VGPR (R10/R12), which is exactly the 2-blocks/CU budget.
//  - hist row stride padded 256->264 ints (R13: 62M bank-conflict cycles;
//    264%32=8 rotates each q-row across banks).
// Structure: tau via two-pass 8b+8b histogram over 4096-row sample
// (33.8KB LDS, overlaid by candidates); CAP 384 (validated R13, passed);
// LDS 74KB -> 2 blocks/CU -> up to 8 waves/SIMD; phase 2 scans m in two
// 2.57MB L2-resident halves.

#define NQ   16384
#define MM   20000
#define DD   64
#define KK   32
#define MPAD 20032
#define NCH  (MPAD / 64)   // 313
#define NW   16            // waves per block
#define QB   32            // queries per block
#define CAP  384           // E~160 (4096-sample tau) + ~7 sigma (R13-validated)
#define HCH  157           // half-split of the chunk range
#define HS   264           // hist row stride (ints), 264%32=8 -> bank rotate

typedef __attribute__((ext_vector_type(8))) short bf16x8;
typedef __attribute__((ext_vector_type(4))) float f32x4;

// ---- workspace layout (bytes) ----
#define OFF_FH 0
#define SZ_FP  (MPAD * DD * 2)
#define OFF_FL (OFF_FH + SZ_FP)
#define OFF_FN (OFF_FL + SZ_FP)
#define SZ_FN  (MPAD * 4)
#define OFF_QH (OFF_FN + SZ_FN)
#define SZ_QP  (NQ * DD * 2)
#define OFF_QL (OFF_QH + SZ_QP)
#define OFF_QN (OFF_QL + SZ_QP)
#define SZ_QN  (NQ * 4)
#define WS_REQ (OFF_QN + SZ_QN)

__device__ __forceinline__ unsigned int bf16_rne(float x) {
    unsigned int xb = __float_as_uint(x);
    return (xb + 0x7fffu + ((xb >> 16) & 1u)) & 0xffff0000u;
}
__device__ __forceinline__ unsigned enc32(float f) {
    unsigned b = __float_as_uint(f);
    return (b & 0x80000000u) ? ~b : (b | 0x80000000u);
}
__device__ __forceinline__ float dec32(unsigned k) {
    unsigned b = (k & 0x80000000u) ? (k & 0x7FFFFFFFu) : ~k;
    return __uint_as_float(b);
}

__global__ void prep_split(const float* __restrict__ src,
                           unsigned short* __restrict__ ph,
                           unsigned short* __restrict__ pl,
                           float* __restrict__ nrm, int nrows_real) {
    const int e = blockIdx.x * 256 + threadIdx.x;
    const int m = e >> 6;
    const int lane = threadIdx.x & 63;
    const bool real = (m < nrows_real);
    float x = real ? src[e] : 0.f;
    unsigned int hb = bf16_rne(x);
    float xh = __uint_as_float(hb);
    unsigned int lb = bf16_rne(x - xh);
    ph[e] = (unsigned short)(hb >> 16);
    pl[e] = (unsigned short)(lb >> 16);
    float s = x * x;
    #pragma unroll
    for (int o = 32; o >= 1; o >>= 1) s += __shfl_xor(s, o);
    if (lane == 0) nrm[m] = real ? s : __builtin_inff();
}

// one subtile: 5 loads, 16 MFMA (4 independent chains), both q-groups.
#define SUBTILE2(c_, t_)                                                       \
    const int frow = (c_) * 64 + (t_) * 16 + q;                                \
    const unsigned short* phh = Fh + (size_t)frow * DD + kof;                  \
    const unsigned short* pll = Fl + (size_t)frow * DD + kof;                  \
    const bf16x8 Ah0 = *(const bf16x8*)(phh);                                  \
    const bf16x8 Ah1 = *(const bf16x8*)(phh + 32);                             \
    const bf16x8 Al0 = *(const bf16x8*)(pll);                                  \
    const bf16x8 Al1 = *(const bf16x8*)(pll + 32);                             \
    const f32x4  fnv = *(const f32x4*)(fn + (c_) * 64 + (t_) * 16 + hgrp * 4); \
    f32x4 a0 = {0.f,0.f,0.f,0.f}, b0 = {0.f,0.f,0.f,0.f};                      \
    f32x4 a1 = {0.f,0.f,0.f,0.f}, b1 = {0.f,0.f,0.f,0.f};                      \
    a0 = __builtin_amdgcn_mfma_f32_16x16x32_bf16(Ah0, qh0A, a0, 0, 0, 0);      \
    b0 = __builtin_amdgcn_mfma_f32_16x16x32_bf16(Ah0, ql0A, b0, 0, 0, 0);      \
    a1 = __builtin_amdgcn_mfma_f32_16x16x32_bf16(Ah0, qh0B, a1, 0, 0, 0);      \
    b1 = __builtin_amdgcn_mfma_f32_16x16x32_bf16(Ah0, ql0B, b1, 0, 0, 0);      \
    a0 = __builtin_amdgcn_mfma_f32_16x16x32_bf16(Ah1, qh1A, a0, 0, 0, 0);      \
    b0 = __builtin_amdgcn_mfma_f32_16x16x32_bf16(Ah1, ql1A, b0, 0, 0, 0);      \
    a1 = __builtin_amdgcn_mfma_f32_16x16x32_bf16(Ah1, qh1B, a1, 0, 0, 0);      \
    b1 = __builtin_amdgcn_mfma_f32_16x16x32_bf16(Ah1, ql1B, b1, 0, 0, 0);      \
    a0 = __builtin_amdgcn_mfma_f32_16x16x32_bf16(Al0, qh0A, a0, 0, 0, 0);      \
    b0 = __builtin_amdgcn_mfma_f32_16x16x32_bf16(Al0, ql0A, b0, 0, 0, 0);      \
    a1 = __builtin_amdgcn_mfma_f32_16x16x32_bf16(Al0, qh0B, a1, 0, 0, 0);      \
    b1 = __builtin_amdgcn_mfma_f32_16x16x32_bf16(Al0, ql0B, b1, 0, 0, 0);      \
    a0 = __builtin_amdgcn_mfma_f32_16x16x32_bf16(Al1, qh1A, a0, 0, 0, 0);      \
    b0 = __builtin_amdgcn_mfma_f32_16x16x32_bf16(Al1, ql1A, b0, 0, 0, 0);      \
    a1 = __builtin_amdgcn_mfma_f32_16x16x32_bf16(Al1, qh1B, a1, 0, 0, 0);      \
    b1 = __builtin_amdgcn_mfma_f32_16x16x32_bf16(Al1, ql1B, b1, 0, 0, 0);      \
    const float sA0 = fnv[0] - 2.f * (a0[0] + b0[0]);                          \
    const float sA1 = fnv[1] - 2.f * (a0[1] + b0[1]);                          \
    const float sA2 = fnv[2] - 2.f * (a0[2] + b0[2]);                          \
    const float sA3 = fnv[3] - 2.f * (a0[3] + b0[3]);                          \
    const float sB0 = fnv[0] - 2.f * (a1[0] + b1[0]);                          \
    const float sB1 = fnv[1] - 2.f * (a1[1] + b1[1]);                          \
    const float sB2 = fnv[2] - 2.f * (a1[2] + b1[2]);                          \
    const float sB3 = fnv[3] - 2.f * (a1[3] + b1[3]);                          \
    const int rb4 = (c_) * 64 + (t_) * 16 + hgrp * 4;

#define GATE2(qq_, tau_, s0_, s1_, s2_, s3_) {                                 \
    const float sv_[4] = {s0_, s1_, s2_, s3_};                                 \
    _Pragma("unroll")                                                          \
    for (int j_ = 0; j_ < 4; ++j_) {                                           \
        if (sv_[j_] <= (tau_)) {                                               \
            const int p_ = atomicAdd(&cnt[qq_], 1);                            \
            if (p_ < CAP) {                                                    \
                bufd[(qq_) * CAP + p_] = sv_[j_];                              \
                bufi[(qq_) * CAP + p_] = (unsigned short)(rb4 + j_);           \
            }                                                                  \
        }                                                                      \
    }                                                                          \
}

// histogram both q-groups' 4 values each; bin extractor BX_(key32)
#define HIST8(BX_, PRED_) {                                                    \
    const unsigned kA0 = enc32(sA0), kA1 = enc32(sA1);                         \
    const unsigned kA2 = enc32(sA2), kA3 = enc32(sA3);                         \
    const unsigned kB0 = enc32(sB0), kB1 = enc32(sB1);                         \
    const unsigned kB2 = enc32(sB2), kB3 = enc32(sB3);                         \
    if (PRED_(kA0, q))      atomicAdd(&hist[q * HS + BX_(kA0)], 1);            \
    if (PRED_(kA1, q))      atomicAdd(&hist[q * HS + BX_(kA1)], 1);            \
    if (PRED_(kA2, q))      atomicAdd(&hist[q * HS + BX_(kA2)], 1);            \
    if (PRED_(kA3, q))      atomicAdd(&hist[q * HS + BX_(kA3)], 1);            \
    if (PRED_(kB0, 16 + q)) atomicAdd(&hist[(16 + q) * HS + BX_(kB0)], 1);     \
    if (PRED_(kB1, 16 + q)) atomicAdd(&hist[(16 + q) * HS + BX_(kB1)], 1);     \
    if (PRED_(kB2, 16 + q)) atomicAdd(&hist[(16 + q) * HS + BX_(kB2)], 1);     \
    if (PRED_(kB3, 16 + q)) atomicAdd(&hist[(16 + q) * HS + BX_(kB3)], 1);     \
}

#define BX_TOP(k_)  ((k_) >> 24)
#define BX_MID(k_)  (((k_) >> 16) & 0xFFu)
#define PR_ALL(k_, qq_)  (1)
#define PR_BIN(k_, qq_)  (((k_) >> 24) == (unsigned)bstar[qq_])

// wave-level select over hist[qq][0..255]: first bin where base+cum >= KK.
#define SELECT256(qq_, base_, SELB_, BELOW_) {                                 \
    const int b0_ = lane * 4;                                                  \
    const int h0_ = hist[(qq_) * HS + b0_ + 0];                                \
    const int h1_ = hist[(qq_) * HS + b0_ + 1];                                \
    const int h2_ = hist[(qq_) * HS + b0_ + 2];                                \
    const int h3_ = hist[(qq_) * HS + b0_ + 3];                                \
    const int c4_ = h0_ + h1_ + h2_ + h3_;                                     \
    int pref_ = c4_;                                                           \
    _Pragma("unroll")                                                          \
    for (int of_ = 1; of_ < 64; of_ <<= 1) {                                   \
        const int t_ = __shfl_up(pref_, of_);                                  \
        if (lane >= of_) pref_ += t_;                                          \
    }                                                                          \
    const unsigned long long mk_ = __ballot((base_) + pref_ >= KK);            \
    const int sel_ = __builtin_ctzll(mk_ | 0x8000000000000000ull);             \
    const int cb_  = __shfl(pref_ - c4_, sel_) + (base_);                      \
    const int g0_ = __shfl(h0_, sel_), g1_ = __shfl(h1_, sel_);                \
    const int g2_ = __shfl(h2_, sel_);                                         \
    int bs_, bl_;                                                              \
    if      (cb_ + g0_ >= KK)             { bs_ = 0; bl_ = cb_; }              \
    else if (cb_ + g0_ + g1_ >= KK)       { bs_ = 1; bl_ = cb_ + g0_; }        \
    else if (cb_ + g0_ + g1_ + g2_ >= KK) { bs_ = 2; bl_ = cb_ + g0_ + g1_; }  \
    else                                  { bs_ = 3; bl_ = cb_ + g0_ + g1_ + g2_; } \
    SELB_ = sel_ * 4 + bs_;                                                    \
    BELOW_ = bl_;                                                              \
}

__global__ __launch_bounds__(1024) void knn_filter32(
    const unsigned short* __restrict__ Fh, const unsigned short* __restrict__ Fl,
    const float* __restrict__ fn,
    const unsigned short* __restrict__ Qh, const unsigned short* __restrict__ Ql,
    const float* __restrict__ qn,
    const float* __restrict__ targets, float* __restrict__ out)
{
    // pool: phase1 = hist u32[32][HS] (33.8KB); phase2/3 = bufd f32[32][CAP]
    // (48KB) + bufi u16[32][CAP] (24KB) = 72KB. pool = 73728 B.
    __shared__ __align__(16) unsigned char pool[QB * CAP * 6];
    __shared__ float tau_f[QB];
    __shared__ int   cnt[QB];
    __shared__ int   bstar[QB];
    __shared__ int   cbel[QB];

    int*            hist = (int*)pool;
    float*          bufd = (float*)pool;
    unsigned short* bufi = (unsigned short*)(pool + QB * CAP * 4);

    const int tid  = threadIdx.x;
    const int lane = tid & 63;
    const int w    = tid >> 6;          // 0..15
    const int qbase = blockIdx.x * QB;
    const int q    = lane & 15;
    const int hgrp = lane >> 4;
    const int kof  = hgrp * 8;

    if (tid < QB) cnt[tid] = 0;
    for (int i = tid; i < QB * HS; i += 1024) hist[i] = 0;

    // stationary Q^T fragments, two query groups
    const int qrow0 = qbase + q;
    const int qrow1 = qbase + 16 + q;
    const bf16x8 qh0A = *(const bf16x8*)(Qh + (size_t)qrow0 * DD + kof);
    const bf16x8 qh1A = *(const bf16x8*)(Qh + (size_t)qrow0 * DD + kof + 32);
    const bf16x8 ql0A = *(const bf16x8*)(Ql + (size_t)qrow0 * DD + kof);
    const bf16x8 ql1A = *(const bf16x8*)(Ql + (size_t)qrow0 * DD + kof + 32);
    const bf16x8 qh0B = *(const bf16x8*)(Qh + (size_t)qrow1 * DD + kof);
    const bf16x8 qh1B = *(const bf16x8*)(Qh + (size_t)qrow1 * DD + kof + 32);
    const bf16x8 ql0B = *(const bf16x8*)(Ql + (size_t)qrow1 * DD + kof);
    const bf16x8 ql1B = *(const bf16x8*)(Ql + (size_t)qrow1 * DD + kof + 32);
    __syncthreads();

    // ===== phase 1a: coarse histogram over sample chunks 0..63 =============
    #pragma unroll
    for (int cc = 0; cc < 4; ++cc) {
        const int chunk = w * 4 + cc;
        #pragma unroll
        for (int t = 0; t < 4; ++t) {
            SUBTILE2(chunk, t)
            (void)rb4;
            HIST8(BX_TOP, PR_ALL)
        }
    }
    __syncthreads();

    // ===== phase 1b: coarse select (wave w owns queries 2w, 2w+1) ==========
    #pragma unroll
    for (int e = 0; e < 2; ++e) {
        const int qq = w * 2 + e;
        int sb, bl;
        SELECT256(qq, 0, sb, bl)
        if (lane == 0) { bstar[qq] = sb; cbel[qq] = bl; }
    }
    __syncthreads();

    // ===== phase 1c: zero hist for fine pass ===============================
    for (int i = tid; i < QB * HS; i += 1024) hist[i] = 0;
    __syncthreads();

    // ===== phase 1d: fine histogram (only values in the coarse bin) ========
    #pragma unroll
    for (int cc = 0; cc < 4; ++cc) {
        const int chunk = w * 4 + cc;
        #pragma unroll
        for (int t = 0; t < 4; ++t) {
            SUBTILE2(chunk, t)
            (void)rb4;
            HIST8(BX_MID, PR_BIN)
        }
    }
    __syncthreads();

    // ===== phase 1e: fine select -> tau ====================================
    #pragma unroll
    for (int e = 0; e < 2; ++e) {
        const int qq = w * 2 + e;
        int sb, bl;
        SELECT256(qq, cbel[qq], sb, bl)
        (void)bl;
        if (lane == 0) {
            const unsigned key16 = ((unsigned)bstar[qq] << 8) | (unsigned)sb;
            tau_f[qq] = (key16 >= 0xFFFFu) ? __builtin_inff()
                                           : dec32((key16 + 1u) << 16);
        }
    }
    __syncthreads();

    // ===== phase 2: full scan in two L2-resident m-halves ==================
    const float tauR0 = tau_f[q];
    const float tauR1 = tau_f[16 + q];
    for (int c = w; c < HCH; c += NW) {
        #pragma unroll
        for (int t = 0; t < 4; ++t) {
            SUBTILE2(c, t)
            GATE2(q,      tauR0, sA0, sA1, sA2, sA3)
            GATE2(16 + q, tauR1, sB0, sB1, sB2, sB3)
        }
    }
    for (int c = HCH + w; c < NCH; c += NW) {
        #pragma unroll
        for (int t = 0; t < 4; ++t) {
            SUBTILE2(c, t)
            GATE2(q,      tauR0, sA0, sA1, sA2, sA3)
            GATE2(16 + q, tauR1, sB0, sB1, sB2, sB3)
        }
    }
    __syncthreads();

    // ===== phase 3: exact rank + weighted sum (2 q per wave) ===============
    #pragma unroll
    for (int e = 0; e < 2; ++e) {
        const int q3 = w * 2 + e;
        const int n  = min(cnt[q3], CAP);
        const float qnv = qn[qbase + q3];

        float    ms[6]; unsigned kk[6]; unsigned short miu[6];
        #pragma unroll
        for (int u = 0; u < 6; ++u) {
            const int j = lane + u * 64;
            const bool v = (j < n);
            ms[u]  = v ? bufd[q3 * CAP + j] : __builtin_inff();
            miu[u] = v ? bufi[q3 * CAP + j] : (unsigned short)0xFFFFu;
            kk[u]  = enc32(ms[u]);
        }
        unsigned lo = 0;
        for (int bit = 31; bit >= 0; --bit) {
            const unsigned trial = lo | (1u << bit);
            int c = 0;
            #pragma unroll
            for (int u = 0; u < 6; ++u) c += (kk[u] < trial);
            #pragma unroll
            for (int o = 32; o >= 1; o >>= 1) c += __shfl_xor(c, o);
            if (c < KK) lo = trial;
        }
        int c0 = 0, tcnt = 0;
        #pragma unroll
        for (int u = 0; u < 6; ++u) { c0 += (kk[u] < lo); tcnt += (kk[u] == lo); }
        #pragma unroll
        for (int o = 32; o >= 1; o >>= 1) {
            c0 += __shfl_xor(c0, o); tcnt += __shfl_xor(tcnt, o);
        }
        const int kprime = KK - c0;
        unsigned ilo = 0xFFFFu;
        if (tcnt != kprime) {
            ilo = 0;
            for (int bit = 15; bit >= 0; --bit) {
                const unsigned trial = ilo | (1u << bit);
                int c = 0;
                #pragma unroll
                for (int u = 0; u < 6; ++u)
                    c += ((kk[u] == lo) && ((unsigned)miu[u] < trial));
                #pragma unroll
                for (int o = 32; o >= 1; o >>= 1) c += __shfl_xor(c, o);
                if (c < kprime) ilo = trial;
            }
        }
        float nume = 0.f, deno = 0.f;
        #pragma unroll
        for (int u = 0; u < 6; ++u) {
            const bool inc = (kk[u] < lo) ||
                             ((kk[u] == lo) && ((unsigned)miu[u] <= ilo));
            if (inc) {
                const float d2 = fmaxf(qnv + ms[u], 0.f);
                const float wv = 1.f / (d2 + 1e-4f);
                nume = fmaf(wv, targets[miu[u]], nume);
                deno += wv;
            }
        }
        #pragma unroll
        for (int o = 32; o >= 1; o >>= 1) {
            nume += __shfl_xor(nume, o);
            deno += __shfl_xor(deno, o);
        }
        if (lane == 0) out[qbase + q3] = nume / fmaxf(deno, 1e-9f);
    }
}

// ---------------- fallback: round-1 exact fp32 vector kernel ----------------
#define BQ 32
#define WQ 8
__global__ __launch_bounds__(256) void hp_knn_kernel(
    const float* __restrict__ points, const float* __restrict__ features,
    const float* __restrict__ targets, float* __restrict__ out)
{
    __shared__ __align__(16) float Qs[BQ][DD];
    __shared__ float qn_s[BQ];
    __shared__ float topd[BQ][KK];
    __shared__ int   topi[BQ][KK];
    const int tid = threadIdx.x, lane = tid & 63, wv = tid >> 6, qb = wv * WQ;
    {
        const float4* src = (const float4*)(points + (size_t)blockIdx.x * BQ * DD);
        float4* dst = (float4*)&Qs[0][0];
        #pragma unroll
        for (int i = 0; i < (BQ * DD / 4) / 256; ++i) dst[tid + i * 256] = src[tid + i * 256];
    }
    for (int i = tid; i < BQ * KK; i += 256) { (&topd[0][0])[i] = __builtin_inff(); (&topi[0][0])[i] = 0; }
    __syncthreads();
    if (tid < BQ) {
        float s = 0.f;
        #pragma unroll
        for (int d = 0; d < DD; ++d) s = fmaf(Qs[tid][d], Qs[tid][d], s);
        qn_s[tid] = s;
    }
    __syncthreads();
    for (int c = 0; c < (MM + 63) / 64; ++c) {
        const int m = c * 64 + lane, mc = (m < MM) ? m : (MM - 1);
        float f[DD];
        const float4* fr = (const float4*)(features + (size_t)mc * DD);
        #pragma unroll
        for (int b = 0; b < DD / 4; ++b) { float4 v = fr[b]; f[4*b]=v.x; f[4*b+1]=v.y; f[4*b+2]=v.z; f[4*b+3]=v.w; }
        float fnv = 0.f;
        #pragma unroll
        for (int d = 0; d < DD; ++d) fnv = fmaf(f[d], f[d], fnv);
        float d2v[WQ];
        #pragma unroll
        for (int qi = 0; qi < WQ; ++qi) {
            const float4* qr = (const float4*)&Qs[qb + qi][0];
            float a0=0,a1=0,a2=0,a3=0;
            #pragma unroll
            for (int b = 0; b < DD / 4; ++b) {
                float4 q4 = qr[b];
                a0 = fmaf(q4.x, f[4*b], a0); a1 = fmaf(q4.y, f[4*b+1], a1);
                a2 = fmaf(q4.z, f[4*b+2], a2); a3 = fmaf(q4.w, f[4*b+3], a3);
            }
            float d2 = fmaxf(qn_s[qb+qi] + fnv - 2.f*((a0+a1)+(a2+a3)), 0.f);
            d2v[qi] = (m < MM) ? d2 : __builtin_inff();
        }
        #pragma unroll
        for (int qi = 0; qi < WQ; ++qi) {
            const int q = qb + qi;
            unsigned long long ball = __ballot(d2v[qi] < topd[q][KK-1]);
            while (ball) {
                const int j = __builtin_ctzll(ball); ball &= ball - 1;
                const float dval = __shfl(d2v[qi], j); const int mval = c * 64 + j;
                if (lane < KK) {
                    const float cur = topd[q][lane];
                    if (cur > dval) {
                        const float pd = (lane > 0) ? topd[q][lane-1] : -1.f;
                        const int   pi = (lane > 0) ? topi[q][lane-1] : 0;
                        const bool tp = (pd > dval);
                        topd[q][lane] = tp ? pd : dval; topi[q][lane] = tp ? pi : mval;
                    }
                }
            }
        }
    }
    #pragma unroll
    for (int qi = 0; qi < WQ; ++qi) {
        const int q = qb + qi;
        float wsum = 0.f, wt = 0.f;
        if (lane < KK) {
            const float ww = 1.f / (topd[q][lane] + 1e-4f);
            wsum = ww; wt = ww * targets[topi[q][lane]];
        }
        #pragma unroll
        for (int o = 32; o >= 1; o >>= 1) { wsum += __shfl_xor(wsum, o); wt += __shfl_xor(wt, o); }
        if (lane == 0) out[(size_t)blockIdx.x * BQ + q] = wt / fmaxf(wsum, 1e-9f);
    }
}

extern "C" void kernel_launch(void* const* d_in, const int* in_sizes, int n_in,
                              void* d_out, int out_size, void* d_ws, size_t ws_size,
                              hipStream_t stream) {
    const float* points   = (const float*)d_in[0];
    const float* features = (const float*)d_in[1];
    const float* targets  = (const float*)d_in[2];
    float* out = (float*)d_out;

    if (ws_size < (size_t)WS_REQ) {
        hp_knn_kernel<<<dim3(NQ / BQ), dim3(256), 0, stream>>>(points, features, targets, out);
        return;
    }
    char* ws = (char*)d_ws;
    unsigned short* Fh = (unsigned short*)(ws + OFF_FH);
    unsigned short* Fl = (unsigned short*)(ws + OFF_FL);
    float*          fn = (float*)(ws + OFF_FN);
    unsigned short* Qh = (unsigned short*)(ws + OFF_QH);
    unsigned short* Ql = (unsigned short*)(ws + OFF_QL);
    float*          qnp= (float*)(ws + OFF_QN);

    prep_split<<<dim3(MPAD * DD / 256), dim3(256), 0, stream>>>(features, Fh, Fl, fn, MM);
    prep_split<<<dim3(NQ * DD / 256),  dim3(256), 0, stream>>>(points,   Qh, Ql, qnp, NQ);
    knn_filter32<<<dim3(NQ / QB), dim3(1024), 0, stream>>>(Fh, Fl, fn, Qh, Ql, qnp, targets, out);
}

// Round 15
// 315.771 us; speedup vs baseline: 4.9790x; 1.5664x over previous
//
#include <hip/hip_runtime.h>
#include <hip/hip_bf16.h>
#include <math.h>

// Split-bf16 MFMA exact-KNN (K=32) + inverse-squared-distance weighting.
// points:[16384,64] features:[20000,64] targets:[20000] -> out:[16384]
//
// Round 15: per-CU traffic floor. 64 q/block, 256 blocks = 1 block/CU ->
// each CU reads the feature planes ONCE (7.35MB/CU vs R10's 10.5MB).
// Validated pieces only: R11's 4-group SUBTILE4 (32 MFMA / 5-load subtile,
// VGPR 64), R14's two-pass 8b+8b histogram tau over 4096-row sample,
// R10's LDS candidate append + exact-rank phase 3. CAP 352 (=E156+7sigma).

#define NQ   16384
#define MM   20000
#define DD   64
#define KK   32
#define MPAD 20032
#define NCH  (MPAD / 64)   // 313
#define NW   16            // waves per block
#define QB   64            // queries per block
#define CAP  352           // E~156 (4096-sample tau) + 7 sigma
#define HS   264           // hist row stride (ints)

typedef __attribute__((ext_vector_type(8))) short bf16x8;
typedef __attribute__((ext_vector_type(4))) float f32x4;

// ---- workspace layout (bytes) ----
#define OFF_FH 0
#define SZ_FP  (MPAD * DD * 2)
#define OFF_FL (OFF_FH + SZ_FP)
#define OFF_FN (OFF_FL + SZ_FP)
#define SZ_FN  (MPAD * 4)
#define OFF_QH (OFF_FN + SZ_FN)
#define SZ_QP  (NQ * DD * 2)
#define OFF_QL (OFF_QH + SZ_QP)
#define OFF_QN (OFF_QL + SZ_QP)
#define SZ_QN  (NQ * 4)
#define WS_REQ (OFF_QN + SZ_QN)

__device__ __forceinline__ unsigned int bf16_rne(float x) {
    unsigned int xb = __float_as_uint(x);
    return (xb + 0x7fffu + ((xb >> 16) & 1u)) & 0xffff0000u;
}
__device__ __forceinline__ unsigned enc32(float f) {
    unsigned b = __float_as_uint(f);
    return (b & 0x80000000u) ? ~b : (b | 0x80000000u);
}
__device__ __forceinline__ float dec32(unsigned k) {
    unsigned b = (k & 0x80000000u) ? (k & 0x7FFFFFFFu) : ~k;
    return __uint_as_float(b);
}

__global__ void prep_split(const float* __restrict__ src,
                           unsigned short* __restrict__ ph,
                           unsigned short* __restrict__ pl,
                           float* __restrict__ nrm, int nrows_real) {
    const int e = blockIdx.x * 256 + threadIdx.x;
    const int m = e >> 6;
    const int lane = threadIdx.x & 63;
    const bool real = (m < nrows_real);
    float x = real ? src[e] : 0.f;
    unsigned int hb = bf16_rne(x);
    float xh = __uint_as_float(hb);
    unsigned int lb = bf16_rne(x - xh);
    ph[e] = (unsigned short)(hb >> 16);
    pl[e] = (unsigned short)(lb >> 16);
    float s = x * x;
    #pragma unroll
    for (int o = 32; o >= 1; o >>= 1) s += __shfl_xor(s, o);
    if (lane == 0) nrm[m] = real ? s : __builtin_inff();
}

// one subtile: 5 loads, 32 MFMA (4 groups x 8, one acc chain per group).
// EPI_(g, s0..s3, rb4) runs per group with g a compile-time constant.
#define SUBTILE4(c_, t_, EPI_)                                                \
  {                                                                           \
    const int rb_ = (c_) * 64 + (t_) * 16;                                    \
    const unsigned short* phh = Fh + (size_t)(rb_ + q) * DD + kof;            \
    const unsigned short* pll = Fl + (size_t)(rb_ + q) * DD + kof;            \
    const bf16x8 Ah0 = *(const bf16x8*)(phh);                                 \
    const bf16x8 Ah1 = *(const bf16x8*)(phh + 32);                            \
    const bf16x8 Al0 = *(const bf16x8*)(pll);                                 \
    const bf16x8 Al1 = *(const bf16x8*)(pll + 32);                            \
    const f32x4  fnv = *(const f32x4*)(fn + rb_ + hgrp * 4);                  \
    const int rb4 = rb_ + hgrp * 4;                                           \
    _Pragma("unroll")                                                         \
    for (int g = 0; g < 4; ++g) {                                             \
      f32x4 a = {0.f, 0.f, 0.f, 0.f};                                         \
      a = __builtin_amdgcn_mfma_f32_16x16x32_bf16(Ah0, qh0[g], a, 0, 0, 0);   \
      a = __builtin_amdgcn_mfma_f32_16x16x32_bf16(Ah1, qh1[g], a, 0, 0, 0);   \
      a = __builtin_amdgcn_mfma_f32_16x16x32_bf16(Ah0, ql0[g], a, 0, 0, 0);   \
      a = __builtin_amdgcn_mfma_f32_16x16x32_bf16(Ah1, ql1[g], a, 0, 0, 0);   \
      a = __builtin_amdgcn_mfma_f32_16x16x32_bf16(Al0, qh0[g], a, 0, 0, 0);   \
      a = __builtin_amdgcn_mfma_f32_16x16x32_bf16(Al1, qh1[g], a, 0, 0, 0);   \
      a = __builtin_amdgcn_mfma_f32_16x16x32_bf16(Al0, ql0[g], a, 0, 0, 0);   \
      a = __builtin_amdgcn_mfma_f32_16x16x32_bf16(Al1, ql1[g], a, 0, 0, 0);   \
      const float s0 = fnv[0] - 2.f * a[0];                                   \
      const float s1 = fnv[1] - 2.f * a[1];                                   \
      const float s2 = fnv[2] - 2.f * a[2];                                   \
      const float s3 = fnv[3] - 2.f * a[3];                                   \
      EPI_(g, s0, s1, s2, s3, rb4)                                            \
    }                                                                         \
  }

#define EPI_HTOP(g_, s0_, s1_, s2_, s3_, rb4_) {                              \
    (void)(rb4_);                                                             \
    const int r_ = ((g_) * 16 + q) * HS;                                      \
    atomicAdd(&hist[r_ + (enc32(s0_) >> 24)], 1);                             \
    atomicAdd(&hist[r_ + (enc32(s1_) >> 24)], 1);                             \
    atomicAdd(&hist[r_ + (enc32(s2_) >> 24)], 1);                             \
    atomicAdd(&hist[r_ + (enc32(s3_) >> 24)], 1);                             \
}

#define EPI_HMID(g_, s0_, s1_, s2_, s3_, rb4_) {                              \
    (void)(rb4_);                                                             \
    const int r_ = ((g_) * 16 + q) * HS;                                      \
    const unsigned bb_ = (unsigned)bst[g_];                                   \
    const unsigned k0_ = enc32(s0_), k1_ = enc32(s1_);                        \
    const unsigned k2_ = enc32(s2_), k3_ = enc32(s3_);                        \
    if ((k0_ >> 24) == bb_) atomicAdd(&hist[r_ + ((k0_ >> 16) & 0xFFu)], 1);  \
    if ((k1_ >> 24) == bb_) atomicAdd(&hist[r_ + ((k1_ >> 16) & 0xFFu)], 1);  \
    if ((k2_ >> 24) == bb_) atomicAdd(&hist[r_ + ((k2_ >> 16) & 0xFFu)], 1);  \
    if ((k3_ >> 24) == bb_) atomicAdd(&hist[r_ + ((k3_ >> 16) & 0xFFu)], 1);  \
}

#define EPI_GATE(g_, s0_, s1_, s2_, s3_, rb4_) {                              \
    const float tq_ = tauR[g_];                                               \
    const int qq_ = (g_) * 16 + q;                                            \
    const float sv_[4] = {s0_, s1_, s2_, s3_};                                \
    _Pragma("unroll")                                                         \
    for (int j_ = 0; j_ < 4; ++j_) {                                          \
      if (sv_[j_] <= tq_) {                                                   \
        const int p_ = atomicAdd(&cnt[qq_], 1);                               \
        if (p_ < CAP) {                                                       \
          bufd[qq_ * CAP + p_] = sv_[j_];                                     \
          bufi[qq_ * CAP + p_] = (unsigned short)((rb4_) + j_);               \
        }                                                                     \
      }                                                                       \
    }                                                                         \
}

// wave-level select over hist[qq][0..255]: first bin where base+cum >= KK.
#define SELECT256(qq_, base_, SELB_, BELOW_) {                                 \
    const int b0_ = lane * 4;                                                  \
    const int h0_ = hist[(qq_) * HS + b0_ + 0];                                \
    const int h1_ = hist[(qq_) * HS + b0_ + 1];                                \
    const int h2_ = hist[(qq_) * HS + b0_ + 2];                                \
    const int h3_ = hist[(qq_) * HS + b0_ + 3];                                \
    const int c4_ = h0_ + h1_ + h2_ + h3_;                                     \
    int pref_ = c4_;                                                           \
    _Pragma("unroll")                                                          \
    for (int of_ = 1; of_ < 64; of_ <<= 1) {                                   \
        const int t_ = __shfl_up(pref_, of_);                                  \
        if (lane >= of_) pref_ += t_;                                          \
    }                                                                          \
    const unsigned long long mk_ = __ballot((base_) + pref_ >= KK);            \
    const int sel_ = __builtin_ctzll(mk_ | 0x8000000000000000ull);             \
    const int cb_  = __shfl(pref_ - c4_, sel_) + (base_);                      \
    const int g0_ = __shfl(h0_, sel_), g1_ = __shfl(h1_, sel_);                \
    const int g2_ = __shfl(h2_, sel_);                                         \
    int bs_, bl_;                                                              \
    if      (cb_ + g0_ >= KK)             { bs_ = 0; bl_ = cb_; }              \
    else if (cb_ + g0_ + g1_ >= KK)       { bs_ = 1; bl_ = cb_ + g0_; }        \
    else if (cb_ + g0_ + g1_ + g2_ >= KK) { bs_ = 2; bl_ = cb_ + g0_ + g1_; }  \
    else                                  { bs_ = 3; bl_ = cb_ + g0_ + g1_ + g2_; } \
    SELB_ = sel_ * 4 + bs_;                                                    \
    BELOW_ = bl_;                                                              \
}

__global__ __launch_bounds__(1024) void knn_filter64(
    const unsigned short* __restrict__ Fh, const unsigned short* __restrict__ Fl,
    const float* __restrict__ fn,
    const unsigned short* __restrict__ Qh, const unsigned short* __restrict__ Ql,
    const float* __restrict__ qn,
    const float* __restrict__ targets, float* __restrict__ out)
{
    // pool: phase1 = hist u32[64][HS] (67.6KB); phase2/3 = bufd f32[64][CAP]
    // (90.1KB... split) + bufi u16[64][CAP]; pool = 64*352*6 = 135168 B.
    __shared__ __align__(16) unsigned char pool[QB * CAP * 6];
    __shared__ float tau_f[QB];
    __shared__ int   cnt[QB];
    __shared__ int   bstar[QB];
    __shared__ int   cbel[QB];

    int*            hist = (int*)pool;
    float*          bufd = (float*)pool;
    unsigned short* bufi = (unsigned short*)(pool + QB * CAP * 4);

    const int tid  = threadIdx.x;
    const int lane = tid & 63;
    const int w    = tid >> 6;          // 0..15
    const int qbase = blockIdx.x * QB;
    const int q    = lane & 15;
    const int hgrp = lane >> 4;
    const int kof  = hgrp * 8;

    if (tid < QB) cnt[tid] = 0;
    for (int i = tid; i < QB * HS; i += 1024) hist[i] = 0;

    // stationary Q^T fragments, 4 query groups
    bf16x8 qh0[4], qh1[4], ql0[4], ql1[4];
    #pragma unroll
    for (int g = 0; g < 4; ++g) {
        const int qrow = qbase + g * 16 + q;
        qh0[g] = *(const bf16x8*)(Qh + (size_t)qrow * DD + kof);
        qh1[g] = *(const bf16x8*)(Qh + (size_t)qrow * DD + kof + 32);
        ql0[g] = *(const bf16x8*)(Ql + (size_t)qrow * DD + kof);
        ql1[g] = *(const bf16x8*)(Ql + (size_t)qrow * DD + kof + 32);
    }
    __syncthreads();

    // ===== phase 1a: coarse histogram over sample chunks 0..63 =============
    #pragma unroll
    for (int cc = 0; cc < 4; ++cc) {
        const int chunk = w * 4 + cc;
        #pragma unroll
        for (int t = 0; t < 4; ++t) {
            SUBTILE4(chunk, t, EPI_HTOP)
        }
    }
    __syncthreads();

    // ===== phase 1b: coarse select (wave w owns queries 4w..4w+3) ==========
    #pragma unroll
    for (int e = 0; e < 4; ++e) {
        const int qq = w * 4 + e;
        int sb, bl;
        SELECT256(qq, 0, sb, bl)
        if (lane == 0) { bstar[qq] = sb; cbel[qq] = bl; }
    }
    __syncthreads();

    int bst[4];
    #pragma unroll
    for (int g = 0; g < 4; ++g) bst[g] = bstar[g * 16 + q];

    // ===== phase 1c: zero hist for fine pass ===============================
    for (int i = tid; i < QB * HS; i += 1024) hist[i] = 0;
    __syncthreads();

    // ===== phase 1d: fine histogram (only values in the coarse bin) ========
    #pragma unroll
    for (int cc = 0; cc < 4; ++cc) {
        const int chunk = w * 4 + cc;
        #pragma unroll
        for (int t = 0; t < 4; ++t) {
            SUBTILE4(chunk, t, EPI_HMID)
        }
    }
    __syncthreads();

    // ===== phase 1e: fine select -> tau ====================================
    #pragma unroll
    for (int e = 0; e < 4; ++e) {
        const int qq = w * 4 + e;
        int sb, bl;
        SELECT256(qq, cbel[qq], sb, bl)
        (void)bl;
        if (lane == 0) {
            const unsigned key16 = ((unsigned)bstar[qq] << 8) | (unsigned)sb;
            tau_f[qq] = (key16 >= 0xFFFFu) ? __builtin_inff()
                                           : dec32((key16 + 1u) << 16);
        }
    }
    __syncthreads();   // hist dead; candidate buffers take over the pool

    // ===== phase 2: full scan, register-tau gated LDS append ===============
    float tauR[4];
    #pragma unroll
    for (int g = 0; g < 4; ++g) tauR[g] = tau_f[g * 16 + q];

    for (int c = w; c < NCH; c += NW) {
        #pragma unroll
        for (int t = 0; t < 4; ++t) {
            SUBTILE4(c, t, EPI_GATE)
        }
    }
    __syncthreads();

    // ===== phase 3: exact rank + weighted sum (4 q per wave) ===============
    #pragma unroll
    for (int e = 0; e < 4; ++e) {
        const int q3 = w * 4 + e;
        const int n  = min(cnt[q3], CAP);
        const float qnv = qn[qbase + q3];

        float    ms[6]; unsigned kk[6]; unsigned short miu[6];
        #pragma unroll
        for (int u = 0; u < 6; ++u) {
            const int j = lane + u * 64;
            const bool v = (j < n);
            ms[u]  = v ? bufd[q3 * CAP + j] : __builtin_inff();
            miu[u] = v ? bufi[q3 * CAP + j] : (unsigned short)0xFFFFu;
            kk[u]  = enc32(ms[u]);
        }
        unsigned lo = 0;
        for (int bit = 31; bit >= 0; --bit) {
            const unsigned trial = lo | (1u << bit);
            int c = 0;
            #pragma unroll
            for (int u = 0; u < 6; ++u) c += (kk[u] < trial);
            #pragma unroll
            for (int o = 32; o >= 1; o >>= 1) c += __shfl_xor(c, o);
            if (c < KK) lo = trial;
        }
        int c0 = 0, tcnt = 0;
        #pragma unroll
        for (int u = 0; u < 6; ++u) { c0 += (kk[u] < lo); tcnt += (kk[u] == lo); }
        #pragma unroll
        for (int o = 32; o >= 1; o >>= 1) {
            c0 += __shfl_xor(c0, o); tcnt += __shfl_xor(tcnt, o);
        }
        const int kprime = KK - c0;
        unsigned ilo = 0xFFFFu;
        if (tcnt != kprime) {
            ilo = 0;
            for (int bit = 15; bit >= 0; --bit) {
                const unsigned trial = ilo | (1u << bit);
                int c = 0;
                #pragma unroll
                for (int u = 0; u < 6; ++u)
                    c += ((kk[u] == lo) && ((unsigned)miu[u] < trial));
                #pragma unroll
                for (int o = 32; o >= 1; o >>= 1) c += __shfl_xor(c, o);
                if (c < kprime) ilo = trial;
            }
        }
        float nume = 0.f, deno = 0.f;
        #pragma unroll
        for (int u = 0; u < 6; ++u) {
            const bool inc = (kk[u] < lo) ||
                             ((kk[u] == lo) && ((unsigned)miu[u] <= ilo));
            if (inc) {
                const float d2 = fmaxf(qnv + ms[u], 0.f);
                const float wv = 1.f / (d2 + 1e-4f);
                nume = fmaf(wv, targets[miu[u]], nume);
                deno += wv;
            }
        }
        #pragma unroll
        for (int o = 32; o >= 1; o >>= 1) {
            nume += __shfl_xor(nume, o);
            deno += __shfl_xor(deno, o);
        }
        if (lane == 0) out[qbase + q3] = nume / fmaxf(deno, 1e-9f);
    }
}

// ---------------- fallback: round-1 exact fp32 vector kernel ----------------
#define BQ 32
#define WQ 8
__global__ __launch_bounds__(256) void hp_knn_kernel(
    const float* __restrict__ points, const float* __restrict__ features,
    const float* __restrict__ targets, float* __restrict__ out)
{
    __shared__ __align__(16) float Qs[BQ][DD];
    __shared__ float qn_s[BQ];
    __shared__ float topd[BQ][KK];
    __shared__ int   topi[BQ][KK];
    const int tid = threadIdx.x, lane = tid & 63, wv = tid >> 6, qb = wv * WQ;
    {
        const float4* src = (const float4*)(points + (size_t)blockIdx.x * BQ * DD);
        float4* dst = (float4*)&Qs[0][0];
        #pragma unroll
        for (int i = 0; i < (BQ * DD / 4) / 256; ++i) dst[tid + i * 256] = src[tid + i * 256];
    }
    for (int i = tid; i < BQ * KK; i += 256) { (&topd[0][0])[i] = __builtin_inff(); (&topi[0][0])[i] = 0; }
    __syncthreads();
    if (tid < BQ) {
        float s = 0.f;
        #pragma unroll
        for (int d = 0; d < DD; ++d) s = fmaf(Qs[tid][d], Qs[tid][d], s);
        qn_s[tid] = s;
    }
    __syncthreads();
    for (int c = 0; c < (MM + 63) / 64; ++c) {
        const int m = c * 64 + lane, mc = (m < MM) ? m : (MM - 1);
        float f[DD];
        const float4* fr = (const float4*)(features + (size_t)mc * DD);
        #pragma unroll
        for (int b = 0; b < DD / 4; ++b) { float4 v = fr[b]; f[4*b]=v.x; f[4*b+1]=v.y; f[4*b+2]=v.z; f[4*b+3]=v.w; }
        float fnv = 0.f;
        #pragma unroll
        for (int d = 0; d < DD; ++d) fnv = fmaf(f[d], f[d], fnv);
        float d2v[WQ];
        #pragma unroll
        for (int qi = 0; qi < WQ; ++qi) {
            const float4* qr = (const float4*)&Qs[qb + qi][0];
            float a0=0,a1=0,a2=0,a3=0;
            #pragma unroll
            for (int b = 0; b < DD / 4; ++b) {
                float4 q4 = qr[b];
                a0 = fmaf(q4.x, f[4*b], a0); a1 = fmaf(q4.y, f[4*b+1], a1);
                a2 = fmaf(q4.z, f[4*b+2], a2); a3 = fmaf(q4.w, f[4*b+3], a3);
            }
            float d2 = fmaxf(qn_s[qb+qi] + fnv - 2.f*((a0+a1)+(a2+a3)), 0.f);
            d2v[qi] = (m < MM) ? d2 : __builtin_inff();
        }
        #pragma unroll
        for (int qi = 0; qi < WQ; ++qi) {
            const int q = qb + qi;
            unsigned long long ball = __ballot(d2v[qi] < topd[q][KK-1]);
            while (ball) {
                const int j = __builtin_ctzll(ball); ball &= ball - 1;
                const float dval = __shfl(d2v[qi], j); const int mval = c * 64 + j;
                if (lane < KK) {
                    const float cur = topd[q][lane];
                    if (cur > dval) {
                        const float pd = (lane > 0) ? topd[q][lane-1] : -1.f;
                        const int   pi = (lane > 0) ? topi[q][lane-1] : 0;
                        const bool tp = (pd > dval);
                        topd[q][lane] = tp ? pd : dval; topi[q][lane] = tp ? pi : mval;
                    }
                }
            }
        }
    }
    #pragma unroll
    for (int qi = 0; qi < WQ; ++qi) {
        const int q = qb + qi;
        float wsum = 0.f, wt = 0.f;
        if (lane < KK) {
            const float ww = 1.f / (topd[q][lane] + 1e-4f);
            wsum = ww; wt = ww * targets[topi[q][lane]];
        }
        #pragma unroll
        for (int o = 32; o >= 1; o >>= 1) { wsum += __shfl_xor(wsum, o); wt += __shfl_xor(wt, o); }
        if (lane == 0) out[(size_t)blockIdx.x * BQ + q] = wt / fmaxf(wsum, 1e-9f);
    }
}

extern "C" void kernel_launch(void* const* d_in, const int* in_sizes, int n_in,
                              void* d_out, int out_size, void* d_ws, size_t ws_size,
                              hipStream_t stream) {
    const float* points   = (const float*)d_in[0];
    const float* features = (const float*)d_in[1];
    const float* targets  = (const float*)d_in[2];
    float* out = (float*)d_out;

    if (ws_size < (size_t)WS_REQ) {
        hp_knn_kernel<<<dim3(NQ / BQ), dim3(256), 0, stream>>>(points, features, targets, out);
        return;
    }
    char* ws = (char*)d_ws;
    unsigned short* Fh = (unsigned short*)(ws + OFF_FH);
    unsigned short* Fl = (unsigned short*)(ws + OFF_FL);
    float*          fn = (float*)(ws + OFF_FN);
    unsigned short* Qh = (unsigned short*)(ws + OFF_QH);
    unsigned short* Ql = (unsigned short*)(ws + OFF_QL);
    float*          qnp= (float*)(ws + OFF_QN);

    prep_split<<<dim3(MPAD * DD / 256), dim3(256), 0, stream>>>(features, Fh, Fl, fn, MM);
    prep_split<<<dim3(NQ * DD / 256),  dim3(256), 0, stream>>>(points,   Qh, Ql, qnp, NQ);
    knn_filter64<<<dim3(NQ / QB), dim3(1024), 0, stream>>>(Fh, Fl, fn, Qh, Ql, qnp, targets, out);
}